// Round 11
// baseline (1537.719 us; speedup 1.0000x reference)
//
#include <hip/hip_runtime.h>
#include <hip/hip_fp16.h>

#define D 128
#define CAP1 80  // d1, d2 buckets (mean degree 32)
#define CAP2 56  // d12, s1, s2 buckets (mean degree 16)

typedef short s16x8 __attribute__((ext_vector_type(8)));
typedef float f32x4 __attribute__((ext_vector_type(4)));

// ===========================================================================
// Two-pass ELL build (replaces the 8x-rescan XCD-partitioned fill; R10 PMC:
// FETCH 149 MB/dispatch = key re-scan thrashing L3).
// Pass 1 (bin): stream edges once, append (key, packed payload) records into
// 8 key-octant segments. Wave-level prefix scan -> 1 atomicAdd per wave per
// octant. Pass 2 (scat): block&7 -> octant; read records contiguously,
// scatter into ELL window (L2-resident per XCD, same cursor semantics).
// Payload packing: (idx << 15) | round(w * 32768)  (err <= 1.5e-5).
// ===========================================================================
struct BinJob {
    const int* key;
    const int* other;
    const float* w;    // nullptr -> raw index payload
    int2* rec;         // 8 segments of capo records
    int* bcur;         // 8 octant counters (zeroed)
    float oscale;      // 8.0f / N  (octant = min(7, key*oscale))
    int capo;          // per-octant segment capacity
    int E;
};
struct BinJobs2 { BinJob j[2]; };

struct ScatJob {
    const int2* rec;
    const int* bcur;
    int* pay;
    int cbase;
    int cap;
    int capo;
};
struct ScatJobs2 { ScatJob j[2]; };

__device__ __forceinline__ int packpay(int o, float w) {
    int w15 = __float2int_rn(w * 32768.0f);
    w15 = w15 > 32767 ? 32767 : w15;
    return (int)(((unsigned)o << 15) | (unsigned)w15);
}

__global__ __launch_bounds__(256) void bin_kernel(BinJobs2 J) {
    BinJob jb = J.j[blockIdx.y];
    bool hasw = (jb.w != nullptr);
    int tid = threadIdx.x;
    int wv = tid >> 6, lane = tid & 63;
    long E = jb.E;
    for (long cb = (long)blockIdx.x * 4096; cb < E;
         cb += (long)gridDim.x * 4096) {
        long wb = cb + (long)wv * 1024;
        if (wb >= E) continue;
        long eb = wb + (long)lane * 16;
        int key[16], oct[16], v[16];
        if (wb + 1024 <= E) {  // full wave chunk: vectorized reads
#pragma unroll
            for (int q = 0; q < 4; ++q) {
                int4 kk = *(const int4*)(jb.key + eb + q * 4);
                int4 oo = *(const int4*)(jb.other + eb + q * 4);
                key[q * 4 + 0] = kk.x; key[q * 4 + 1] = kk.y;
                key[q * 4 + 2] = kk.z; key[q * 4 + 3] = kk.w;
                if (hasw) {
                    float4 ww = *(const float4*)(jb.w + eb + q * 4);
                    v[q * 4 + 0] = packpay(oo.x, ww.x);
                    v[q * 4 + 1] = packpay(oo.y, ww.y);
                    v[q * 4 + 2] = packpay(oo.z, ww.z);
                    v[q * 4 + 3] = packpay(oo.w, ww.w);
                } else {
                    v[q * 4 + 0] = oo.x; v[q * 4 + 1] = oo.y;
                    v[q * 4 + 2] = oo.z; v[q * 4 + 3] = oo.w;
                }
            }
        } else {  // tail: guarded scalar reads
#pragma unroll
            for (int i = 0; i < 16; ++i) {
                long e = eb + i;
                if (e < E) {
                    key[i] = jb.key[e];
                    int o = jb.other[e];
                    v[i] = hasw ? packpay(o, jb.w[e]) : o;
                } else {
                    key[i] = -1;
                }
            }
        }
#pragma unroll
        for (int i = 0; i < 16; ++i) {
            int oc = (int)((float)key[i] * jb.oscale);
            oct[i] = (key[i] < 0) ? -1 : (oc > 7 ? 7 : oc);
        }
        // per-octant wave append: shfl prefix -> one atomic per wave
        for (int o = 0; o < 8; ++o) {
            int cnt = 0;
#pragma unroll
            for (int i = 0; i < 16; ++i) cnt += (oct[i] == o);
            int incl = cnt;
            for (int d = 1; d < 64; d <<= 1) {
                int t = __shfl_up(incl, d, 64);
                if (lane >= d) incl += t;
            }
            int total = __shfl(incl, 63, 64);
            if (total == 0) continue;
            int base = 0;
            if (lane == 63) base = atomicAdd(jb.bcur + o, total);
            base = __shfl(base, 63, 64);
            int s = base + incl - cnt;
            int2* seg = jb.rec + (long)o * jb.capo;
#pragma unroll
            for (int i = 0; i < 16; ++i) {
                if (oct[i] == o) {
                    if (s < jb.capo) seg[s] = make_int2(key[i], v[i]);
                    ++s;
                }
            }
        }
    }
}

__global__ __launch_bounds__(256) void scat_kernel(ScatJobs2 J,
                                                   int* __restrict__ cursor) {
    ScatJob jb = J.j[blockIdx.y];
    int o = blockIdx.x & 7;   // octant ~ XCD
    int gb = blockIdx.x >> 3;
    int cnt = jb.bcur[o];
    if (cnt > jb.capo) cnt = jb.capo;
    const int2* seg = jb.rec + (long)o * jb.capo;
    long stride = (long)(gridDim.x >> 3) * 256;
    for (long i = (long)gb * 256 + threadIdx.x; i < cnt; i += stride) {
        int2 r = seg[i];
        int pos = atomicAdd(&cursor[jb.cbase + r.x], 1);
        if (pos < jb.cap) jb.pay[(long)r.x * jb.cap + pos] = r.y;
    }
}

// ===========================================================================
// fp32 -> fp16 conversion (x_node table)
// ===========================================================================
__global__ void f2h_kernel(const float2* __restrict__ in, __half2* __restrict__ o,
                           long n2) {
    long i = (long)blockIdx.x * blockDim.x + threadIdx.x;
    if (i < n2) o[i] = __float22half2_rn(in[i]);
}

// ===========================================================================
// Split W (3 x 128 x 128 fp32) into bf16 hi/lo pair: W = hi + lo + O(2^-16).
// ===========================================================================
__global__ void wsplit_kernel(const float* __restrict__ W1,
                              const float* __restrict__ W2,
                              const float* __restrict__ W12,
                              unsigned short* __restrict__ hi,
                              unsigned short* __restrict__ lo) {
    int i = blockIdx.x * 256 + threadIdx.x;
    if (i >= 3 * D * D) return;
    int p = i >> 14, r = i & (D * D - 1);
    const float* W = p == 0 ? W1 : (p == 1 ? W2 : W12);
    float x = W[r];
    unsigned u = __float_as_uint(x);
    unsigned hb = u & 0xFFFF0000u;
    hi[i] = (unsigned short)(hb >> 16);
    float rem = x - __uint_as_float(hb);
    lo[i] = (unsigned short)(__float_as_uint(rem) >> 16);
}

// ===========================================================================
// Wide-gather aggregation: 16B/lane float4 loads. R1/R2 established these
// kernels are L2-miss-path bound (dur == FETCH/3.1TB/s); lowest-VGPR form.
// ===========================================================================
__device__ __forceinline__ void acc8(float4 raw, float mul, float2 a[4]) {
    const __half2* h = (const __half2*)&raw;
#pragma unroll
    for (int k = 0; k < 4; ++k) {
        float2 f = __half22float2(h[k]);
        a[k].x = fmaf(f.x, mul, a[k].x);
        a[k].y = fmaf(f.y, mul, a[k].y);
    }
}

// Stage-1: gather fp16 rows, fp32 accumulate, combine with fp32 xb,
// write fp16 row at dst[node*dstride + doff]. One wave per node.
template <bool HASW>
__global__ __launch_bounds__(256) void aggh_kernel(
    const __half* __restrict__ vals, int vstride, const int* __restrict__ cnt,
    int cap, const int* __restrict__ pay, const float* __restrict__ xb,
    __half* __restrict__ dst, int dstride, int doff, int N) {
    int node = (int)(((long)blockIdx.x * 256 + threadIdx.x) >> 6);
    int lane = threadIdx.x & 63;
    if (node >= N) return;
    int count = cnt[node];
    int m = count < cap ? count : cap;
    long b0 = (long)node * cap;
    int grp = lane >> 4, il = lane & 15;
    float2 a[4] = {{0.f, 0.f}, {0.f, 0.f}, {0.f, 0.f}, {0.f, 0.f}};
    for (int base = 0; base < m; base += 64) {
        int rem = m - base;
        int n = rem < 64 ? rem : 64;
        int p = 0;
        if (lane < n) p = pay[b0 + base + lane];
        for (int j = 0; j < n; j += 4) {
            int jj = j + grp;
            int pj = __shfl(p, jj, 64);
            int g;
            float wt;
            if (HASW) {
                g = (int)(((unsigned)pj) >> 15);
                wt = (float)(pj & 0x7fff) * (1.0f / 32768.0f);
            } else {
                g = pj;
                wt = 1.0f;
            }
            float mul = jj < n ? wt : 0.0f;
            float4 raw = ((const float4*)(vals + (long)g * vstride))[il];
            acc8(raw, mul, a);
        }
    }
#pragma unroll
    for (int k = 0; k < 4; ++k) {
        a[k].x += __shfl_xor(a[k].x, 16, 64);
        a[k].y += __shfl_xor(a[k].y, 16, 64);
        a[k].x += __shfl_xor(a[k].x, 32, 64);
        a[k].y += __shfl_xor(a[k].y, 32, 64);
    }
    if (lane < 16) {
        float inv = 1.0f / fmaxf((float)count, 1.0f);
        const float4* xp = (const float4*)(xb + (long)node * D + il * 8);
        float4 x0 = xp[0], x1 = xp[1];
        float rx[8] = {x0.x, x0.y, x0.z, x0.w, x1.x, x1.y, x1.z, x1.w};
        __half2 h[4];
#pragma unroll
        for (int k = 0; k < 4; ++k) {
            float2 r;
            r.x = (a[k].x * inv + rx[2 * k + 0]) * 0.5f;
            r.y = (a[k].y * inv + rx[2 * k + 1]) * 0.5f;
            h[k] = __float22half2_rn(r);
        }
        *(float4*)(dst + (long)node * dstride + doff + il * 8) = *(float4*)h;
    }
}

// Stage-2: pre1 = mean over fp16 net1h rows, fp32 output, no combine.
__global__ __launch_bounds__(256) void aggf_kernel(
    const __half* __restrict__ vals, const int* __restrict__ cnt, int cap,
    const int* __restrict__ pay, float* __restrict__ out, int N) {
    int node = (int)(((long)blockIdx.x * 256 + threadIdx.x) >> 6);
    int lane = threadIdx.x & 63;
    if (node >= N) return;
    int count = cnt[node];
    int m = count < cap ? count : cap;
    long b0 = (long)node * cap;
    int grp = lane >> 4, il = lane & 15;
    float2 a[4] = {{0.f, 0.f}, {0.f, 0.f}, {0.f, 0.f}, {0.f, 0.f}};
    for (int base = 0; base < m; base += 64) {
        int rem = m - base;
        int n = rem < 64 ? rem : 64;
        int p = 0;
        if (lane < n) p = pay[b0 + base + lane];
        for (int j = 0; j < n; j += 4) {
            int jj = j + grp;
            int pj = __shfl(p, jj, 64);
            float mul = jj < n ? 1.0f : 0.0f;
            float4 raw = ((const float4*)(vals + (long)pj * D))[il];
            acc8(raw, mul, a);
        }
    }
#pragma unroll
    for (int k = 0; k < 4; ++k) {
        a[k].x += __shfl_xor(a[k].x, 16, 64);
        a[k].y += __shfl_xor(a[k].y, 16, 64);
        a[k].x += __shfl_xor(a[k].x, 32, 64);
        a[k].y += __shfl_xor(a[k].y, 32, 64);
    }
    if (lane < 16) {
        float inv = 1.0f / fmaxf((float)count, 1.0f);
        float4* op = (float4*)(out + (long)node * D + il * 8);
        float4 o0 = {a[0].x * inv, a[0].y * inv, a[1].x * inv, a[1].y * inv};
        float4 o1 = {a[2].x * inv, a[2].y * inv, a[3].x * inv, a[3].y * inv};
        op[0] = o0;
        op[1] = o1;
    }
}

// Fused pre2/pre3: combo rows hold [net2h | net2bh] (256 halves, 512B).
// Requires cap <= 64 (cap = CAP2 = 56): single payload batch.
__global__ __launch_bounds__(256) void agg2_kernel(
    const __half* __restrict__ combo, const int* __restrict__ cnt, int cap,
    const int* __restrict__ pay, float* __restrict__ outa,
    float* __restrict__ outb, int N) {
    int node = (int)(((long)blockIdx.x * 256 + threadIdx.x) >> 6);
    int lane = threadIdx.x & 63;
    if (node >= N) return;
    int count = cnt[node];
    int m = count < cap ? count : cap;
    long b0 = (long)node * cap;
    int grp = lane >> 5, il = lane & 31;
    float2 a[4] = {{0.f, 0.f}, {0.f, 0.f}, {0.f, 0.f}, {0.f, 0.f}};
    int p = 0;
    if (lane < m) p = pay[b0 + lane];
    for (int j = 0; j < m; j += 2) {
        int jj = j + grp;
        int pj = __shfl(p, jj, 64);
        int g = (int)(((unsigned)pj) >> 15);
        float w = (float)(pj & 0x7fff) * (1.0f / 32768.0f);
        float mul = jj < m ? (il < 16 ? 1.0f : w) : 0.0f;
        float4 raw = ((const float4*)(combo + (long)g * 256))[il];
        acc8(raw, mul, a);
    }
#pragma unroll
    for (int k = 0; k < 4; ++k) {
        a[k].x += __shfl_xor(a[k].x, 32, 64);
        a[k].y += __shfl_xor(a[k].y, 32, 64);
    }
    if (lane < 32) {
        float inv = 1.0f / fmaxf((float)count, 1.0f);
        float* o = (il < 16) ? (outa + (long)node * D + il * 8)
                             : (outb + (long)node * D + (il - 16) * 8);
        float4 o0 = {a[0].x * inv, a[0].y * inv, a[1].x * inv, a[1].y * inv};
        float4 o1 = {a[2].x * inv, a[2].y * inv, a[3].x * inv, a[3].y * inv};
        ((float4*)o)[0] = o0;
        ((float4*)o)[1] = o1;
    }
}

// ===========================================================================
// MFMA tail v4 (unchanged from R10): split-bf16 MFMA, LDS-staged W,
// 16x64 per-wave tile, 2 blocks/CU, sred aliased into wlds.
// ===========================================================================
#define LO_OFF 32768  // lo table offset in wlds

__device__ __forceinline__ int wswz(int r, int s) {
    return r * 256 + ((s ^ (r & 7)) << 4);
}

__global__ __launch_bounds__(512, 2) void mfma_tail_kernel(
    const float* __restrict__ pre1, const float* __restrict__ pre2,
    const float* pre3, const unsigned short* __restrict__ Whi,
    const unsigned short* __restrict__ Wlo, const float* __restrict__ b1,
    const float* __restrict__ b2, const float* __restrict__ b12,
    const float* __restrict__ att, float* out, int N) {
    __shared__ __align__(16) char wlds[2 * 128 * 256];  // 65536 B: hi | lo
    int tid = threadIdx.x;
    int wv = tid >> 6, lane = tid & 63;
    int strip = wv >> 1, half = wv & 1;
    int rw = lane & 15, kg = lane >> 4;
    int m0 = blockIdx.x * 64 + strip * 16;
    int mrow = m0 + rw;
    if (mrow >= N) mrow = N - 1;  // clamp; no early return (barriers below)
    const float* PRE[3] = {pre1, pre2, pre3};
    const float* BB[3] = {b1, b2, b12};

    f32x4 acc[3][4];
#pragma unroll
    for (int p = 0; p < 3; ++p)
#pragma unroll
        for (int c = 0; c < 4; ++c) acc[p][c] = (f32x4){0.f, 0.f, 0.f, 0.f};

    for (int p = 0; p < 3; ++p) {
        const unsigned short* WH = Whi + ((long)p << 14);
        const unsigned short* WL = Wlo + ((long)p << 14);
#pragma unroll
        for (int c = 0; c < 4; ++c) {
            int idx = tid + c * 512;      // 0..2047
            int r = idx >> 4, s = idx & 15;
            int dst = wswz(r, s);
            *(float4*)(wlds + dst) = *(const float4*)(WH + r * D + s * 8);
            *(float4*)(wlds + LO_OFF + dst) =
                *(const float4*)(WL + r * D + s * 8);
        }
        __syncthreads();

        const float* src = PRE[p] + (long)mrow * D + kg * 8;
#pragma unroll
        for (int kt = 0; kt < 4; ++kt) {
            float4 xa = *(const float4*)(src + kt * 32);
            float4 xb = *(const float4*)(src + kt * 32 + 4);
            float xs[8] = {xa.x, xa.y, xa.z, xa.w, xb.x, xb.y, xb.z, xb.w};
            s16x8 ah, al;
#pragma unroll
            for (int i = 0; i < 8; ++i) {
                unsigned u = __float_as_uint(xs[i]);
                unsigned hb = u & 0xFFFF0000u;
                ah[i] = (short)(hb >> 16);
                float rem = xs[i] - __uint_as_float(hb);
                al[i] = (short)(__float_as_uint(rem) >> 16);
            }
#pragma unroll
            for (int c = 0; c < 4; ++c) {
                const char* bp =
                    wlds + wswz(half * 64 + c * 16 + rw, kt * 4 + kg);
                s16x8 bh = *(const s16x8*)bp;
                s16x8 bl = *(const s16x8*)(bp + LO_OFF);
                acc[p][c] = __builtin_amdgcn_mfma_f32_16x16x32_bf16(
                    ah, bh, acc[p][c], 0, 0, 0);
                acc[p][c] = __builtin_amdgcn_mfma_f32_16x16x32_bf16(
                    ah, bl, acc[p][c], 0, 0, 0);
                acc[p][c] = __builtin_amdgcn_mfma_f32_16x16x32_bf16(
                    al, bh, acc[p][c], 0, 0, 0);
            }
        }
        __syncthreads();
    }

    float sc[3][4] = {{0.f, 0.f, 0.f, 0.f},
                      {0.f, 0.f, 0.f, 0.f},
                      {0.f, 0.f, 0.f, 0.f}};
#pragma unroll
    for (int p = 0; p < 3; ++p) {
#pragma unroll
        for (int c = 0; c < 4; ++c) {
            int col = half * 64 + c * 16 + rw;
            float bv = BB[p][col];
            float av = att[p * D + col];
#pragma unroll
            for (int j = 0; j < 4; ++j) {
                float v = fmaxf(acc[p][c][j] + bv, 0.0f);
                acc[p][c][j] = v;
                sc[p][j] = fmaf(v, av, sc[p][j]);
            }
        }
    }
#pragma unroll
    for (int j = 0; j < 4; ++j) {
#pragma unroll
        for (int off = 1; off < 16; off <<= 1) {
            sc[0][j] += __shfl_xor(sc[0][j], off, 64);
            sc[1][j] += __shfl_xor(sc[1][j], off, 64);
            sc[2][j] += __shfl_xor(sc[2][j], off, 64);
        }
    }
    float* sred = (float*)wlds;
    if (rw == 0) {
#pragma unroll
        for (int p = 0; p < 3; ++p)
#pragma unroll
            for (int j = 0; j < 4; ++j)
                sred[((strip * 2 + half) * 3 + p) * 16 + kg * 4 + j] = sc[p][j];
    }
    __syncthreads();

#pragma unroll
    for (int j = 0; j < 4; ++j) {
        int row = kg * 4 + j;
        float s0 = sred[((strip * 2 + 0) * 3 + 0) * 16 + row] +
                   sred[((strip * 2 + 1) * 3 + 0) * 16 + row];
        float s1 = sred[((strip * 2 + 0) * 3 + 1) * 16 + row] +
                   sred[((strip * 2 + 1) * 3 + 1) * 16 + row];
        float s2 = sred[((strip * 2 + 0) * 3 + 2) * 16 + row] +
                   sred[((strip * 2 + 1) * 3 + 2) * 16 + row];
        float mx = fmaxf(s0, fmaxf(s1, s2));
        float e0 = __expf(s0 - mx), e1 = __expf(s1 - mx), e2 = __expf(s2 - mx);
        float inv = 1.0f / (e0 + e1 + e2);
        float w0 = e0 * inv, w1 = e1 * inv, w2 = e2 * inv;
        int orow = m0 + row;
        if (orow < N) {
            long ro = (long)orow * D + half * 64 + rw;
#pragma unroll
            for (int c = 0; c < 4; ++c) {
                out[ro + c * 16] =
                    acc[0][c][j] * w0 + acc[1][c][j] * w1 + acc[2][c][j] * w2;
            }
        }
    }
}

// ===========================================================================
extern "C" void kernel_launch(void* const* d_in, const int* in_sizes, int n_in,
                              void* d_out, int out_size, void* d_ws,
                              size_t ws_size, hipStream_t stream) {
    const float* x_node = (const float*)d_in[0];
    const float* x1 = (const float*)d_in[1];
    const float* x2 = (const float*)d_in[2];
    const int* ei1_src = (const int*)d_in[3];
    const int* ei1_dst = (const int*)d_in[4];
    const int* ei2_src = (const int*)d_in[5];
    const int* ei2_dst = (const int*)d_in[6];
    const int* ei12_src = (const int*)d_in[7];
    const int* ei12_dst = (const int*)d_in[8];
    const float* ew1 = (const float*)d_in[9];
    const float* ew2 = (const float*)d_in[10];
    const float* W1 = (const float*)d_in[11];
    const float* b1 = (const float*)d_in[12];
    const float* W2 = (const float*)d_in[13];
    const float* b2 = (const float*)d_in[14];
    const float* W12 = (const float*)d_in[15];
    const float* b12 = (const float*)d_in[16];
    const float* att = (const float*)d_in[17];
    float* out = (float*)d_out;

    const int N0 = in_sizes[0] / D;
    const int N1 = in_sizes[1] / D;
    const int N2 = in_sizes[2] / D;
    const int E1 = in_sizes[3];
    const int E2 = in_sizes[5];
    const int E12 = in_sizes[7];

    float* ws = (float*)d_ws;
    size_t off = 0;
    auto A = [](size_t v) { return (v + 3) & ~(size_t)3; };  // 16B align (words)

    // fp16 tables
    __half* xh = (__half*)(ws + off);    off += A((size_t)N0 * D / 2);
    size_t off_net = off;  // records region base (net1h+combo, dead in fills)
    __half* net1h = (__half*)(ws + off); off += A((size_t)N1 * D / 2);
    __half* combo = (__half*)(ws + off); off += A((size_t)N2 * D);  // 256 h/row

    // --- ELL payload block A: pay_d12, pay_s1 (dead after aggf) ---
    // pre2 aliases this block (written by agg2, after both are dead).
    size_t pA = off;
    int* pay_d12 = (int*)(ws + off); off += A((size_t)N2 * CAP2);
    int* pay_s1 = (int*)(ws + off);  off += A((size_t)N0 * CAP2);
    size_t needA = pA + (size_t)N0 * D;  // pre2 words
    if (off < needA) off = needA;
    float* pre2 = ws + pA;

    // --- ELL payload block B: pay_d1, pay_d2 (dead after aggh d1/d2) ---
    // pre1 aliases this block (written by aggf, after both are dead).
    size_t pB = off;
    int* pay_d1 = (int*)(ws + off); off += A((size_t)N1 * CAP1);
    int* pay_d2 = (int*)(ws + off); off += A((size_t)N2 * CAP1);
    size_t needB = pB + (size_t)N0 * D;  // pre1 words
    if (off < needB) off = needB;
    float* pre1 = ws + pB;

    int* pay_s2 = (int*)(ws + off); off += A((size_t)N0 * CAP2);
    float* pre3 = out;  // d_out doubles as pre3 scratch

    // split-bf16 weight tables (hi/lo), [3][128][128]
    unsigned short* Whi = (unsigned short*)(ws + off); off += A((size_t)3 * D * D / 2);
    unsigned short* Wlo = (unsigned short*)(ws + off); off += A((size_t)3 * D * D / 2);

    // concatenated cursors [d1:N1][d2:N2][d12:N2][s1:N0][s2:N0] + bcur[40]
    const int NT = N1 + 2 * N2 + 2 * N0;
    int* cur = (int*)(ws + off); off += A(NT + 40);
    int* bcur = cur + NT;  // 5 jobs x 8 octant counters
    const int cb_d1 = 0, cb_d2 = N1, cb_d12 = N1 + N2;
    const int cb_s1 = N1 + 2 * N2, cb_s2 = N1 + 2 * N2 + N0;

    hipMemsetAsync((void*)cur, 0, (size_t)(NT + 40) * sizeof(int), stream);

    // x_node -> fp16; W -> split bf16
    long n2 = (long)N0 * D / 2;
    f2h_kernel<<<(n2 + 255) / 256, 256, 0, stream>>>((const float2*)x_node,
                                                     (__half2*)xh, n2);
    wsplit_kernel<<<(3 * D * D + 255) / 256, 256, 0, stream>>>(W1, W2, W12,
                                                               Whi, Wlo);

    // --- two-pass ELL build, 3 groups (records alias net1h+combo: 38.4 MB)
    // capo = E/8 + E/32 + 1024 (~120 sigma above binomial mean)
    auto capof = [](int E) { return E / 8 + E / 32 + 1024; };
    int capo1 = capof(E1), capo2 = capof(E2), capo12 = capof(E12);
    int2* recA = (int2*)(ws + off_net);  // first job of each group
    // group 1: {d1, d12}  (scatter windows 2.0 + 0.7 MB per XCD)
    int2* rec_d12 = recA + (size_t)8 * capo1;
    BinJob bd1 = {ei1_dst, ei1_src, ew1, recA, bcur + 0, 8.0f / N1, capo1, E1};
    BinJob bd12 = {ei12_dst, ei12_src, nullptr, rec_d12, bcur + 8,
                   8.0f / N2, capo12, E12};
    BinJobs2 B1 = {{bd1, bd12}};
    bin_kernel<<<dim3(1024, 2), 256, 0, stream>>>(B1);
    ScatJob sd1 = {recA, bcur + 0, pay_d1, cb_d1, CAP1, capo1};
    ScatJob sd12 = {rec_d12, bcur + 8, pay_d12, cb_d12, CAP2, capo12};
    ScatJobs2 S1 = {{sd1, sd12}};
    scat_kernel<<<dim3(4096, 2), 256, 0, stream>>>(S1, cur);
    // group 2: {d2, s1}  (windows 2.0 + 1.4 MB per XCD)
    int2* rec_s1 = recA + (size_t)8 * capo2;
    BinJob bd2 = {ei2_dst, ei2_src, ew2, recA, bcur + 16, 8.0f / N2, capo2, E2};
    BinJob bs1 = {ei1_src, ei1_dst, nullptr, rec_s1, bcur + 24,
                  8.0f / N0, capo1, E1};
    BinJobs2 B2 = {{bd2, bs1}};
    bin_kernel<<<dim3(1024, 2), 256, 0, stream>>>(B2);
    ScatJob sd2 = {recA, bcur + 16, pay_d2, cb_d2, CAP1, capo2};
    ScatJob ss1 = {rec_s1, bcur + 24, pay_s1, cb_s1, CAP2, capo1};
    ScatJobs2 S2 = {{sd2, ss1}};
    scat_kernel<<<dim3(4096, 2), 256, 0, stream>>>(S2, cur);
    // group 3: {s2}  (window 1.4 MB per XCD)
    BinJob bs2 = {ei2_src, ei2_dst, ew2, recA, bcur + 32, 8.0f / N0, capo2, E2};
    BinJobs2 B3 = {{bs2, bs2}};
    bin_kernel<<<dim3(1024, 1), 256, 0, stream>>>(B3);
    ScatJob ss2 = {recA, bcur + 32, pay_s2, cb_s2, CAP2, capo2};
    ScatJobs2 S3 = {{ss2, ss2}};
    scat_kernel<<<dim3(4096, 1), 256, 0, stream>>>(S3, cur);

    // aggregations
    auto blocks = [](int n) { return (n + 3) / 4; };
    aggh_kernel<true><<<blocks(N1), 256, 0, stream>>>(
        xh, D, cur + cb_d1, CAP1, pay_d1, x1, net1h, D, 0, N1);
    aggh_kernel<true><<<blocks(N2), 256, 0, stream>>>(
        xh, D, cur + cb_d2, CAP1, pay_d2, x2, combo, 2 * D, 0, N2);
    aggh_kernel<false><<<blocks(N2), 256, 0, stream>>>(
        net1h, D, cur + cb_d12, CAP2, pay_d12, x2, combo, 2 * D, D, N2);
    aggf_kernel<<<blocks(N0), 256, 0, stream>>>(net1h, cur + cb_s1, CAP2,
                                                pay_s1, pre1, N0);
    agg2_kernel<<<blocks(N0), 256, 0, stream>>>(combo, cur + cb_s2, CAP2,
                                                pay_s2, pre2, pre3, N0);

    // fused MFMA tail: 3x(linear+relu) + attention (pre3 aliases out)
    mfma_tail_kernel<<<(N0 + 63) / 64, 512, 0, stream>>>(
        pre1, pre2, pre3, Whi, Wlo, b1, b2, b12, att, out, N0);
}

// Round 12
// 918.058 us; speedup vs baseline: 1.6750x; 1.6750x over previous
//
#include <hip/hip_runtime.h>
#include <hip/hip_fp16.h>

#define D 128
#define CAP1 80  // d1, d2 buckets (mean degree 32)
#define CAP2 56  // d12, s1, s2 buckets (mean degree 16)
#define NBLK 1024  // bin sub-segment blocks

typedef short s16x8 __attribute__((ext_vector_type(8)));
typedef float f32x4 __attribute__((ext_vector_type(4)));

// ===========================================================================
// Two-pass ELL build, v2 (R11 post-mortem: global octant counters on one
// cache line bounced across 8 XCD L2s -> 300us serialized bins; scat was
// only ~74us total, proving XCD-local scatter is cheap).
// Pass 1 (bin): each block owns a CONTIGUOUS edge range; bins into 8
// LDS-counted per-block sub-segments rec[blk][oct][capb] (LDS atomicAdd,
// zero cross-block contention; 24KB/block region written once, L2-resident).
// Pass 2 (scat): block&7 -> octant ~ XCD; walk that octant's sub-segments,
// scatter into the ELL window (cursor + window L2-local, as R11 proved).
// Payload packing: (idx << 15) | round(w * 32768)  (err <= 1.5e-5).
// ===========================================================================
struct BinJob {
    const int* key;
    const int* other;
    const float* w;    // nullptr -> raw index payload
    int2* rec;         // [NBLK][8][capb]
    int* bcur;         // [NBLK][8] counts (written unconditionally)
    float oscale;      // 8.0f / N
    int capb;          // per-(block,octant) capacity
    int E;
    int per;           // edges per block
};

struct ScatJob {
    const int2* rec;
    const int* bcur;
    int* pay;
    int cbase;
    int cap;
    int capb;
};

__device__ __forceinline__ int packpay(int o, float w) {
    int w15 = __float2int_rn(w * 32768.0f);
    w15 = w15 > 32767 ? 32767 : w15;
    return (int)(((unsigned)o << 15) | (unsigned)w15);
}

__global__ __launch_bounds__(256) void bin_kernel(BinJob jb) {
    __shared__ int lcur[8];
    int tid = threadIdx.x;
    if (tid < 8) lcur[tid] = 0;
    __syncthreads();
    long lo = (long)blockIdx.x * jb.per;
    long hi = lo + jb.per;
    if (hi > jb.E) hi = jb.E;
    bool hasw = (jb.w != nullptr);
    int2* myrec = jb.rec + (long)blockIdx.x * 8 * jb.capb;
    for (long e = lo + tid; e < hi; e += 256) {
        int k = jb.key[e];
        int o = jb.other[e];
        int v = hasw ? packpay(o, jb.w[e]) : o;
        int oc = (int)((float)k * jb.oscale);
        oc = oc > 7 ? 7 : oc;
        int pos = atomicAdd(&lcur[oc], 1);  // LDS atomic: block-local
        if (pos < jb.capb) myrec[oc * jb.capb + pos] = make_int2(k, v);
    }
    __syncthreads();
    if (tid < 8) {
        int c = lcur[tid];
        jb.bcur[blockIdx.x * 8 + tid] = c < jb.capb ? c : jb.capb;
    }
}

__global__ __launch_bounds__(256) void scat_kernel(ScatJob jb,
                                                   int* __restrict__ cursor) {
    int o = blockIdx.x & 7;   // octant ~ XCD
    int gb = blockIdx.x >> 3;
    int nb = gridDim.x >> 3;
    int tid = threadIdx.x;
    for (int b = gb; b < NBLK; b += nb) {
        int cnt = jb.bcur[b * 8 + o];
        const int2* seg = jb.rec + ((long)b * 8 + o) * jb.capb;
        for (int i = tid; i < cnt; i += 256) {
            int2 r = seg[i];
            int pos = atomicAdd(&cursor[jb.cbase + r.x], 1);
            if (pos < jb.cap) jb.pay[(long)r.x * jb.cap + pos] = r.y;
        }
    }
}

// ===========================================================================
// fp32 -> fp16 conversion (x_node table)
// ===========================================================================
__global__ void f2h_kernel(const float2* __restrict__ in, __half2* __restrict__ o,
                           long n2) {
    long i = (long)blockIdx.x * blockDim.x + threadIdx.x;
    if (i < n2) o[i] = __float22half2_rn(in[i]);
}

// ===========================================================================
// Split W (3 x 128 x 128 fp32) into bf16 hi/lo pair: W = hi + lo + O(2^-16).
// ===========================================================================
__global__ void wsplit_kernel(const float* __restrict__ W1,
                              const float* __restrict__ W2,
                              const float* __restrict__ W12,
                              unsigned short* __restrict__ hi,
                              unsigned short* __restrict__ lo) {
    int i = blockIdx.x * 256 + threadIdx.x;
    if (i >= 3 * D * D) return;
    int p = i >> 14, r = i & (D * D - 1);
    const float* W = p == 0 ? W1 : (p == 1 ? W2 : W12);
    float x = W[r];
    unsigned u = __float_as_uint(x);
    unsigned hb = u & 0xFFFF0000u;
    hi[i] = (unsigned short)(hb >> 16);
    float rem = x - __uint_as_float(hb);
    lo[i] = (unsigned short)(__float_as_uint(rem) >> 16);
}

// ===========================================================================
// Wide-gather aggregation: 16B/lane float4 loads. R1/R2 established these
// kernels are L2-miss-path bound (dur == FETCH/3.1TB/s); lowest-VGPR form.
// ===========================================================================
__device__ __forceinline__ void acc8(float4 raw, float mul, float2 a[4]) {
    const __half2* h = (const __half2*)&raw;
#pragma unroll
    for (int k = 0; k < 4; ++k) {
        float2 f = __half22float2(h[k]);
        a[k].x = fmaf(f.x, mul, a[k].x);
        a[k].y = fmaf(f.y, mul, a[k].y);
    }
}

// Stage-1: gather fp16 rows, fp32 accumulate, combine with fp32 xb,
// write fp16 row at dst[node*dstride + doff]. One wave per node.
template <bool HASW>
__global__ __launch_bounds__(256) void aggh_kernel(
    const __half* __restrict__ vals, int vstride, const int* __restrict__ cnt,
    int cap, const int* __restrict__ pay, const float* __restrict__ xb,
    __half* __restrict__ dst, int dstride, int doff, int N) {
    int node = (int)(((long)blockIdx.x * 256 + threadIdx.x) >> 6);
    int lane = threadIdx.x & 63;
    if (node >= N) return;
    int count = cnt[node];
    int m = count < cap ? count : cap;
    long b0 = (long)node * cap;
    int grp = lane >> 4, il = lane & 15;
    float2 a[4] = {{0.f, 0.f}, {0.f, 0.f}, {0.f, 0.f}, {0.f, 0.f}};
    for (int base = 0; base < m; base += 64) {
        int rem = m - base;
        int n = rem < 64 ? rem : 64;
        int p = 0;
        if (lane < n) p = pay[b0 + base + lane];
        for (int j = 0; j < n; j += 4) {
            int jj = j + grp;
            int pj = __shfl(p, jj, 64);
            int g;
            float wt;
            if (HASW) {
                g = (int)(((unsigned)pj) >> 15);
                wt = (float)(pj & 0x7fff) * (1.0f / 32768.0f);
            } else {
                g = pj;
                wt = 1.0f;
            }
            float mul = jj < n ? wt : 0.0f;
            float4 raw = ((const float4*)(vals + (long)g * vstride))[il];
            acc8(raw, mul, a);
        }
    }
#pragma unroll
    for (int k = 0; k < 4; ++k) {
        a[k].x += __shfl_xor(a[k].x, 16, 64);
        a[k].y += __shfl_xor(a[k].y, 16, 64);
        a[k].x += __shfl_xor(a[k].x, 32, 64);
        a[k].y += __shfl_xor(a[k].y, 32, 64);
    }
    if (lane < 16) {
        float inv = 1.0f / fmaxf((float)count, 1.0f);
        const float4* xp = (const float4*)(xb + (long)node * D + il * 8);
        float4 x0 = xp[0], x1 = xp[1];
        float rx[8] = {x0.x, x0.y, x0.z, x0.w, x1.x, x1.y, x1.z, x1.w};
        __half2 h[4];
#pragma unroll
        for (int k = 0; k < 4; ++k) {
            float2 r;
            r.x = (a[k].x * inv + rx[2 * k + 0]) * 0.5f;
            r.y = (a[k].y * inv + rx[2 * k + 1]) * 0.5f;
            h[k] = __float22half2_rn(r);
        }
        *(float4*)(dst + (long)node * dstride + doff + il * 8) = *(float4*)h;
    }
}

// Stage-2: pre1 = mean over fp16 net1h rows, fp32 output, no combine.
__global__ __launch_bounds__(256) void aggf_kernel(
    const __half* __restrict__ vals, const int* __restrict__ cnt, int cap,
    const int* __restrict__ pay, float* __restrict__ out, int N) {
    int node = (int)(((long)blockIdx.x * 256 + threadIdx.x) >> 6);
    int lane = threadIdx.x & 63;
    if (node >= N) return;
    int count = cnt[node];
    int m = count < cap ? count : cap;
    long b0 = (long)node * cap;
    int grp = lane >> 4, il = lane & 15;
    float2 a[4] = {{0.f, 0.f}, {0.f, 0.f}, {0.f, 0.f}, {0.f, 0.f}};
    for (int base = 0; base < m; base += 64) {
        int rem = m - base;
        int n = rem < 64 ? rem : 64;
        int p = 0;
        if (lane < n) p = pay[b0 + base + lane];
        for (int j = 0; j < n; j += 4) {
            int jj = j + grp;
            int pj = __shfl(p, jj, 64);
            float mul = jj < n ? 1.0f : 0.0f;
            float4 raw = ((const float4*)(vals + (long)pj * D))[il];
            acc8(raw, mul, a);
        }
    }
#pragma unroll
    for (int k = 0; k < 4; ++k) {
        a[k].x += __shfl_xor(a[k].x, 16, 64);
        a[k].y += __shfl_xor(a[k].y, 16, 64);
        a[k].x += __shfl_xor(a[k].x, 32, 64);
        a[k].y += __shfl_xor(a[k].y, 32, 64);
    }
    if (lane < 16) {
        float inv = 1.0f / fmaxf((float)count, 1.0f);
        float4* op = (float4*)(out + (long)node * D + il * 8);
        float4 o0 = {a[0].x * inv, a[0].y * inv, a[1].x * inv, a[1].y * inv};
        float4 o1 = {a[2].x * inv, a[2].y * inv, a[3].x * inv, a[3].y * inv};
        op[0] = o0;
        op[1] = o1;
    }
}

// Fused pre2/pre3: combo rows hold [net2h | net2bh] (256 halves, 512B).
// Requires cap <= 64 (cap = CAP2 = 56): single payload batch.
__global__ __launch_bounds__(256) void agg2_kernel(
    const __half* __restrict__ combo, const int* __restrict__ cnt, int cap,
    const int* __restrict__ pay, float* __restrict__ outa,
    float* __restrict__ outb, int N) {
    int node = (int)(((long)blockIdx.x * 256 + threadIdx.x) >> 6);
    int lane = threadIdx.x & 63;
    if (node >= N) return;
    int count = cnt[node];
    int m = count < cap ? count : cap;
    long b0 = (long)node * cap;
    int grp = lane >> 5, il = lane & 31;
    float2 a[4] = {{0.f, 0.f}, {0.f, 0.f}, {0.f, 0.f}, {0.f, 0.f}};
    int p = 0;
    if (lane < m) p = pay[b0 + lane];
    for (int j = 0; j < m; j += 2) {
        int jj = j + grp;
        int pj = __shfl(p, jj, 64);
        int g = (int)(((unsigned)pj) >> 15);
        float w = (float)(pj & 0x7fff) * (1.0f / 32768.0f);
        float mul = jj < m ? (il < 16 ? 1.0f : w) : 0.0f;
        float4 raw = ((const float4*)(combo + (long)g * 256))[il];
        acc8(raw, mul, a);
    }
#pragma unroll
    for (int k = 0; k < 4; ++k) {
        a[k].x += __shfl_xor(a[k].x, 32, 64);
        a[k].y += __shfl_xor(a[k].y, 32, 64);
    }
    if (lane < 32) {
        float inv = 1.0f / fmaxf((float)count, 1.0f);
        float* o = (il < 16) ? (outa + (long)node * D + il * 8)
                             : (outb + (long)node * D + (il - 16) * 8);
        float4 o0 = {a[0].x * inv, a[0].y * inv, a[1].x * inv, a[1].y * inv};
        float4 o1 = {a[2].x * inv, a[2].y * inv, a[3].x * inv, a[3].y * inv};
        ((float4*)o)[0] = o0;
        ((float4*)o)[1] = o1;
    }
}

// ===========================================================================
// MFMA tail v4 (unchanged from R10): split-bf16 MFMA, LDS-staged W,
// 16x64 per-wave tile, 2 blocks/CU, sred aliased into wlds.
// ===========================================================================
#define LO_OFF 32768  // lo table offset in wlds

__device__ __forceinline__ int wswz(int r, int s) {
    return r * 256 + ((s ^ (r & 7)) << 4);
}

__global__ __launch_bounds__(512, 2) void mfma_tail_kernel(
    const float* __restrict__ pre1, const float* __restrict__ pre2,
    const float* pre3, const unsigned short* __restrict__ Whi,
    const unsigned short* __restrict__ Wlo, const float* __restrict__ b1,
    const float* __restrict__ b2, const float* __restrict__ b12,
    const float* __restrict__ att, float* out, int N) {
    __shared__ __align__(16) char wlds[2 * 128 * 256];  // 65536 B: hi | lo
    int tid = threadIdx.x;
    int wv = tid >> 6, lane = tid & 63;
    int strip = wv >> 1, half = wv & 1;
    int rw = lane & 15, kg = lane >> 4;
    int m0 = blockIdx.x * 64 + strip * 16;
    int mrow = m0 + rw;
    if (mrow >= N) mrow = N - 1;  // clamp; no early return (barriers below)
    const float* PRE[3] = {pre1, pre2, pre3};
    const float* BB[3] = {b1, b2, b12};

    f32x4 acc[3][4];
#pragma unroll
    for (int p = 0; p < 3; ++p)
#pragma unroll
        for (int c = 0; c < 4; ++c) acc[p][c] = (f32x4){0.f, 0.f, 0.f, 0.f};

    for (int p = 0; p < 3; ++p) {
        const unsigned short* WH = Whi + ((long)p << 14);
        const unsigned short* WL = Wlo + ((long)p << 14);
#pragma unroll
        for (int c = 0; c < 4; ++c) {
            int idx = tid + c * 512;      // 0..2047
            int r = idx >> 4, s = idx & 15;
            int dst = wswz(r, s);
            *(float4*)(wlds + dst) = *(const float4*)(WH + r * D + s * 8);
            *(float4*)(wlds + LO_OFF + dst) =
                *(const float4*)(WL + r * D + s * 8);
        }
        __syncthreads();

        const float* src = PRE[p] + (long)mrow * D + kg * 8;
#pragma unroll
        for (int kt = 0; kt < 4; ++kt) {
            float4 xa = *(const float4*)(src + kt * 32);
            float4 xb = *(const float4*)(src + kt * 32 + 4);
            float xs[8] = {xa.x, xa.y, xa.z, xa.w, xb.x, xb.y, xb.z, xb.w};
            s16x8 ah, al;
#pragma unroll
            for (int i = 0; i < 8; ++i) {
                unsigned u = __float_as_uint(xs[i]);
                unsigned hb = u & 0xFFFF0000u;
                ah[i] = (short)(hb >> 16);
                float rem = xs[i] - __uint_as_float(hb);
                al[i] = (short)(__float_as_uint(rem) >> 16);
            }
#pragma unroll
            for (int c = 0; c < 4; ++c) {
                const char* bp =
                    wlds + wswz(half * 64 + c * 16 + rw, kt * 4 + kg);
                s16x8 bh = *(const s16x8*)bp;
                s16x8 bl = *(const s16x8*)(bp + LO_OFF);
                acc[p][c] = __builtin_amdgcn_mfma_f32_16x16x32_bf16(
                    ah, bh, acc[p][c], 0, 0, 0);
                acc[p][c] = __builtin_amdgcn_mfma_f32_16x16x32_bf16(
                    ah, bl, acc[p][c], 0, 0, 0);
                acc[p][c] = __builtin_amdgcn_mfma_f32_16x16x32_bf16(
                    al, bh, acc[p][c], 0, 0, 0);
            }
        }
        __syncthreads();
    }

    float sc[3][4] = {{0.f, 0.f, 0.f, 0.f},
                      {0.f, 0.f, 0.f, 0.f},
                      {0.f, 0.f, 0.f, 0.f}};
#pragma unroll
    for (int p = 0; p < 3; ++p) {
#pragma unroll
        for (int c = 0; c < 4; ++c) {
            int col = half * 64 + c * 16 + rw;
            float bv = BB[p][col];
            float av = att[p * D + col];
#pragma unroll
            for (int j = 0; j < 4; ++j) {
                float v = fmaxf(acc[p][c][j] + bv, 0.0f);
                acc[p][c][j] = v;
                sc[p][j] = fmaf(v, av, sc[p][j]);
            }
        }
    }
#pragma unroll
    for (int j = 0; j < 4; ++j) {
#pragma unroll
        for (int off = 1; off < 16; off <<= 1) {
            sc[0][j] += __shfl_xor(sc[0][j], off, 64);
            sc[1][j] += __shfl_xor(sc[1][j], off, 64);
            sc[2][j] += __shfl_xor(sc[2][j], off, 64);
        }
    }
    float* sred = (float*)wlds;
    if (rw == 0) {
#pragma unroll
        for (int p = 0; p < 3; ++p)
#pragma unroll
            for (int j = 0; j < 4; ++j)
                sred[((strip * 2 + half) * 3 + p) * 16 + kg * 4 + j] = sc[p][j];
    }
    __syncthreads();

#pragma unroll
    for (int j = 0; j < 4; ++j) {
        int row = kg * 4 + j;
        float s0 = sred[((strip * 2 + 0) * 3 + 0) * 16 + row] +
                   sred[((strip * 2 + 1) * 3 + 0) * 16 + row];
        float s1 = sred[((strip * 2 + 0) * 3 + 1) * 16 + row] +
                   sred[((strip * 2 + 1) * 3 + 1) * 16 + row];
        float s2 = sred[((strip * 2 + 0) * 3 + 2) * 16 + row] +
                   sred[((strip * 2 + 1) * 3 + 2) * 16 + row];
        float mx = fmaxf(s0, fmaxf(s1, s2));
        float e0 = __expf(s0 - mx), e1 = __expf(s1 - mx), e2 = __expf(s2 - mx);
        float inv = 1.0f / (e0 + e1 + e2);
        float w0 = e0 * inv, w1 = e1 * inv, w2 = e2 * inv;
        int orow = m0 + row;
        if (orow < N) {
            long ro = (long)orow * D + half * 64 + rw;
#pragma unroll
            for (int c = 0; c < 4; ++c) {
                out[ro + c * 16] =
                    acc[0][c][j] * w0 + acc[1][c][j] * w1 + acc[2][c][j] * w2;
            }
        }
    }
}

// ===========================================================================
extern "C" void kernel_launch(void* const* d_in, const int* in_sizes, int n_in,
                              void* d_out, int out_size, void* d_ws,
                              size_t ws_size, hipStream_t stream) {
    const float* x_node = (const float*)d_in[0];
    const float* x1 = (const float*)d_in[1];
    const float* x2 = (const float*)d_in[2];
    const int* ei1_src = (const int*)d_in[3];
    const int* ei1_dst = (const int*)d_in[4];
    const int* ei2_src = (const int*)d_in[5];
    const int* ei2_dst = (const int*)d_in[6];
    const int* ei12_src = (const int*)d_in[7];
    const int* ei12_dst = (const int*)d_in[8];
    const float* ew1 = (const float*)d_in[9];
    const float* ew2 = (const float*)d_in[10];
    const float* W1 = (const float*)d_in[11];
    const float* b1 = (const float*)d_in[12];
    const float* W2 = (const float*)d_in[13];
    const float* b2 = (const float*)d_in[14];
    const float* W12 = (const float*)d_in[15];
    const float* b12 = (const float*)d_in[16];
    const float* att = (const float*)d_in[17];
    float* out = (float*)d_out;

    const int N0 = in_sizes[0] / D;
    const int N1 = in_sizes[1] / D;
    const int N2 = in_sizes[2] / D;
    const int E1 = in_sizes[3];
    const int E2 = in_sizes[5];
    const int E12 = in_sizes[7];

    float* ws = (float*)d_ws;
    size_t off = 0;
    auto A = [](size_t v) { return (v + 3) & ~(size_t)3; };  // 16B align (words)

    // fp16 tables
    __half* xh = (__half*)(ws + off);    off += A((size_t)N0 * D / 2);
    size_t off_net = off;  // records region base (net1h+combo, dead in fills)
    __half* net1h = (__half*)(ws + off); off += A((size_t)N1 * D / 2);
    __half* combo = (__half*)(ws + off); off += A((size_t)N2 * D);  // 256 h/row

    // --- ELL payload block A: pay_d12, pay_s1 (dead after aggf) ---
    // pre2 aliases this block (written by agg2, after both are dead).
    size_t pA = off;
    int* pay_d12 = (int*)(ws + off); off += A((size_t)N2 * CAP2);
    int* pay_s1 = (int*)(ws + off);  off += A((size_t)N0 * CAP2);
    size_t needA = pA + (size_t)N0 * D;  // pre2 words
    if (off < needA) off = needA;
    float* pre2 = ws + pA;

    // --- ELL payload block B: pay_d1, pay_d2 (dead after aggh d1/d2) ---
    // pre1 aliases this block (written by aggf, after both are dead).
    size_t pB = off;
    int* pay_d1 = (int*)(ws + off); off += A((size_t)N1 * CAP1);
    int* pay_d2 = (int*)(ws + off); off += A((size_t)N2 * CAP1);
    size_t needB = pB + (size_t)N0 * D;  // pre1 words
    if (off < needB) off = needB;
    float* pre1 = ws + pB;

    int* pay_s2 = (int*)(ws + off); off += A((size_t)N0 * CAP2);
    float* pre3 = out;  // d_out doubles as pre3 scratch

    // split-bf16 weight tables (hi/lo), [3][128][128]
    unsigned short* Whi = (unsigned short*)(ws + off); off += A((size_t)3 * D * D / 2);
    unsigned short* Wlo = (unsigned short*)(ws + off); off += A((size_t)3 * D * D / 2);

    // concatenated cursors [d1:N1][d2:N2][d12:N2][s1:N0][s2:N0] (zeroed)
    // + bcur [NBLK][8] (written unconditionally by bin; no memset needed)
    const int NT = N1 + 2 * N2 + 2 * N0;
    int* cur = (int*)(ws + off); off += A(NT);
    int* bcur = (int*)(ws + off); off += A((size_t)NBLK * 8);
    const int cb_d1 = 0, cb_d2 = N1, cb_d12 = N1 + N2;
    const int cb_s1 = N1 + 2 * N2, cb_s2 = N1 + 2 * N2 + N0;

    hipMemsetAsync((void*)cur, 0, (size_t)NT * sizeof(int), stream);

    // x_node -> fp16; W -> split bf16
    long n2 = (long)N0 * D / 2;
    f2h_kernel<<<(n2 + 255) / 256, 256, 0, stream>>>((const float2*)x_node,
                                                     (__half2*)xh, n2);
    wsplit_kernel<<<(3 * D * D + 255) / 256, 256, 0, stream>>>(W1, W2, W12,
                                                               Whi, Wlo);

    // --- two-pass ELL build, one job at a time (records alias net1h+combo;
    // scat_j drains before bin_{j+1} reuses the region — stream order) ---
    int2* rec = (int2*)(ws + off_net);
    struct JobDesc {
        const int* key; const int* other; const float* w;
        int* pay; int cbase; int cap; int E; int N;
    } JD[5] = {
        {ei1_dst, ei1_src, ew1, pay_d1, cb_d1, CAP1, E1, N1},
        {ei2_dst, ei2_src, ew2, pay_d2, cb_d2, CAP1, E2, N2},
        {ei12_dst, ei12_src, nullptr, pay_d12, cb_d12, CAP2, E12, N2},
        {ei1_src, ei1_dst, nullptr, pay_s1, cb_s1, CAP2, E1, N0},
        {ei2_src, ei2_dst, ew2, pay_s2, cb_s2, CAP2, E2, N0},
    };
    for (int j = 0; j < 5; ++j) {
        int per = (JD[j].E + NBLK - 1) / NBLK;
        int capb = per / 8 + per / 16 + 64;  // ~+8 sigma binomial slack
        BinJob bj = {JD[j].key, JD[j].other, JD[j].w, rec, bcur,
                     8.0f / JD[j].N, capb, JD[j].E, per};
        bin_kernel<<<NBLK, 256, 0, stream>>>(bj);
        ScatJob sj = {rec, bcur, JD[j].pay, JD[j].cbase, JD[j].cap, capb};
        scat_kernel<<<4096, 256, 0, stream>>>(sj, cur);
    }

    // aggregations
    auto blocks = [](int n) { return (n + 3) / 4; };
    aggh_kernel<true><<<blocks(N1), 256, 0, stream>>>(
        xh, D, cur + cb_d1, CAP1, pay_d1, x1, net1h, D, 0, N1);
    aggh_kernel<true><<<blocks(N2), 256, 0, stream>>>(
        xh, D, cur + cb_d2, CAP1, pay_d2, x2, combo, 2 * D, 0, N2);
    aggh_kernel<false><<<blocks(N2), 256, 0, stream>>>(
        net1h, D, cur + cb_d12, CAP2, pay_d12, x2, combo, 2 * D, D, N2);
    aggf_kernel<<<blocks(N0), 256, 0, stream>>>(net1h, cur + cb_s1, CAP2,
                                                pay_s1, pre1, N0);
    agg2_kernel<<<blocks(N0), 256, 0, stream>>>(combo, cur + cb_s2, CAP2,
                                                pay_s2, pre2, pre3, N0);

    // fused MFMA tail: 3x(linear+relu) + attention (pre3 aliases out)
    mfma_tail_kernel<<<(N0 + 63) / 64, 512, 0, stream>>>(
        pre1, pre2, pre3, Whi, Wlo, b1, b2, b12, att, out, N0);
}